// Round 1
// baseline (152.526 us; speedup 1.0000x reference)
//
#include <hip/hip_runtime.h>
#include <hip/hip_bf16.h>

typedef __bf16 bf16_t;
typedef bf16_t bf16x8 __attribute__((ext_vector_type(8)));
typedef bf16_t bf16x4 __attribute__((ext_vector_type(4)));
typedef float  f32x4  __attribute__((ext_vector_type(4)));

__device__ __forceinline__ f32x4 mfma16(bf16x8 a, bf16x8 b, f32x4 c) {
  return __builtin_amdgcn_mfma_f32_16x16x32_bf16(a, b, c, 0, 0, 0);
}

// ---------------- cast f32 -> bf16 (vectorized x4) ----------------
__global__ __launch_bounds__(256) void cast_bf16_k(const float* __restrict__ in,
                                                   bf16_t* __restrict__ out, int n4) {
  int i = blockIdx.x * 256 + threadIdx.x;
  if (i >= n4) return;
  float4 v = reinterpret_cast<const float4*>(in)[i];
  bf16x4 o = { (bf16_t)v.x, (bf16_t)v.y, (bf16_t)v.z, (bf16_t)v.w };
  reinterpret_cast<bf16x4*>(out)[i] = o;
}

// ---------------- GEMM: C[M,N] = A[M,K] * B[N,K]^T, bf16 in, f32 out ------------
// 128x128 tile, BK=64, 4 waves (2x2 of 64x64), global_load_lds staging with
// XOR-swizzle (linear LDS dest + inverse-swizzled global source + swizzled read).
__global__ __launch_bounds__(256) void gemm_bt(const bf16_t* __restrict__ A,
                                               const bf16_t* __restrict__ B,
                                               float* __restrict__ C,
                                               int M, int N, int K) {
  __shared__ __align__(16) unsigned short sA[128 * 64];
  __shared__ __align__(16) unsigned short sB[128 * 64];
  const int tid = threadIdx.x;
  const int lane = tid & 63;
  const int wid = tid >> 6;
  const int wm = wid >> 1, wn = wid & 1;
  const int lr = lane & 15, lg = lane >> 4;
  const int m0 = blockIdx.y * 128, n0 = blockIdx.x * 128;

  f32x4 acc[4][4] = {};

  for (int k0 = 0; k0 < K; k0 += 64) {
#pragma unroll
    for (int r = 0; r < 4; ++r) {
      int e = r * 2048 + tid * 8;            // flat elem within 128x64 tile
      int row = e >> 6;                      // tile row
      int c = ((e >> 3) & 7) ^ (row & 7);    // inverse-swizzled logical chunk
      const bf16_t* ga = A + (size_t)(m0 + row) * K + k0 + c * 8;
      __builtin_amdgcn_global_load_lds(
          (const __attribute__((address_space(1))) void*)ga,
          (__attribute__((address_space(3))) void*)(sA + r * 2048 + wid * 512), 16, 0, 0);
      const bf16_t* gb = B + (size_t)(n0 + row) * K + k0 + c * 8;
      __builtin_amdgcn_global_load_lds(
          (const __attribute__((address_space(1))) void*)gb,
          (__attribute__((address_space(3))) void*)(sB + r * 2048 + wid * 512), 16, 0, 0);
    }
    __syncthreads();   // compiler drains vmcnt before barrier -> LDS tiles ready
#pragma unroll
    for (int ks = 0; ks < 2; ++ks) {
      bf16x8 afr[4], bfr[4];
#pragma unroll
      for (int m = 0; m < 4; ++m) {
        int row = wm * 64 + m * 16 + lr;
        int sc = (ks * 4 + lg) ^ (row & 7);  // swizzled read chunk
        afr[m] = *reinterpret_cast<const bf16x8*>(sA + row * 64 + sc * 8);
      }
#pragma unroll
      for (int n = 0; n < 4; ++n) {
        int row = wn * 64 + n * 16 + lr;
        int sc = (ks * 4 + lg) ^ (row & 7);
        bfr[n] = *reinterpret_cast<const bf16x8*>(sB + row * 64 + sc * 8);
      }
#pragma unroll
      for (int m = 0; m < 4; ++m)
#pragma unroll
        for (int n = 0; n < 4; ++n)
          acc[m][n] = mfma16(afr[m], bfr[n], acc[m][n]);
    }
    __syncthreads();   // reads done before next stage overwrites
  }
#pragma unroll
  for (int m = 0; m < 4; ++m)
#pragma unroll
    for (int n = 0; n < 4; ++n) {
      int row = m0 + wm * 64 + m * 16 + lg * 4;
      int col = n0 + wn * 64 + n * 16 + lr;
#pragma unroll
      for (int r2 = 0; r2 < 4; ++r2)
        C[(size_t)(row + r2) * N + col] = acc[m][n][r2];
    }
}

// ---------------- RMSNorm of q (1024) and k (256) rows, emit bf16 ----------------
// qkv row layout: [0..1023]=q, [1024..1279]=k, [1280..1535]=v
__global__ __launch_bounds__(256) void rmsnorm_k(const float* __restrict__ qkv,
                                                 const float* __restrict__ qw,
                                                 const float* __restrict__ kw,
                                                 bf16_t* __restrict__ qn,
                                                 bf16_t* __restrict__ kn) {
  const int row = blockIdx.x;          // 0..4095 = b*2048 + s
  const int b = row >> 11, s = row & 2047;
  const int tid = threadIdx.x;
  const float* rp = qkv + (size_t)row * 1536;
  float4 q4 = *reinterpret_cast<const float4*>(rp + tid * 4);
  float kv1 = rp[1024 + tid];
  float sq = q4.x * q4.x + q4.y * q4.y + q4.z * q4.z + q4.w * q4.w;
  float sk = kv1 * kv1;
#pragma unroll
  for (int d = 1; d < 64; d <<= 1) {
    sq += __shfl_xor(sq, d, 64);
    sk += __shfl_xor(sk, d, 64);
  }
  __shared__ float red[2][4];
  if ((tid & 63) == 0) { red[0][tid >> 6] = sq; red[1][tid >> 6] = sk; }
  __syncthreads();
  sq = red[0][0] + red[0][1] + red[0][2] + red[0][3];
  sk = red[1][0] + red[1][1] + red[1][2] + red[1][3];
  const float rq = rsqrtf(sq * (1.0f / 1024.0f) + 1e-6f);
  const float rk = rsqrtf(sk * (1.0f / 256.0f) + 1e-6f);
  float4 w4 = *reinterpret_cast<const float4*>(qw + tid * 4);
  const int c = tid * 4, hh = c >> 6, d0 = c & 63;
  bf16x4 o = { (bf16_t)(q4.x * rq * w4.x), (bf16_t)(q4.y * rq * w4.y),
               (bf16_t)(q4.z * rq * w4.z), (bf16_t)(q4.w * rq * w4.w) };
  *reinterpret_cast<bf16x4*>(qn + ((size_t)((b * 16 + hh) * 2048 + s)) * 64 + d0) = o;
  const int kvh = tid >> 6, dk = tid & 63;
  kn[((size_t)((b * 4 + kvh) * 2048 + s)) * 64 + dk] = (bf16_t)(kv1 * rk * kw[tid]);
}

// ---------------- V transpose: qkv[.,1280+kv*64+d] -> vt[b][kv][d][s] bf16 -------
__global__ __launch_bounds__(256) void transpose_v_k(const float* __restrict__ qkv,
                                                     bf16_t* __restrict__ vt) {
  __shared__ float t[64][65];
  const int s0 = blockIdx.x * 64;
  const int b = blockIdx.y >> 2, kv = blockIdx.y & 3;
  const int tid = threadIdx.x;
  const int r = tid >> 2, cg = (tid & 3) * 16;
  const float* src = qkv + (size_t)(b * 2048 + s0 + r) * 1536 + 1280 + kv * 64 + cg;
#pragma unroll
  for (int j = 0; j < 4; ++j) {
    float4 v = *reinterpret_cast<const float4*>(src + j * 4);
    t[r][cg + j * 4 + 0] = v.x; t[r][cg + j * 4 + 1] = v.y;
    t[r][cg + j * 4 + 2] = v.z; t[r][cg + j * 4 + 3] = v.w;
  }
  __syncthreads();
  const int dl = tid >> 4;           // 0..15
  const int sl = (tid & 15) * 4;     // 0..60
#pragma unroll
  for (int p = 0; p < 4; ++p) {
    const int d = dl + p * 16;
    bf16x4 o = { (bf16_t)t[sl + 0][d], (bf16_t)t[sl + 1][d],
                 (bf16_t)t[sl + 2][d], (bf16_t)t[sl + 3][d] };
    *reinterpret_cast<bf16x4*>(vt + ((size_t)((b * 4 + kv) * 64 + d)) * 2048 + s0 + sl) = o;
  }
}

// ---------------- Flash attention: sliding-window causal + ALiBi ----------------
// 4 waves/block, 16 q-rows per wave, 32-key tiles, online softmax in exp2 domain.
__global__ __launch_bounds__(256) void attn_k(const bf16_t* __restrict__ qn,
                                              const bf16_t* __restrict__ kn,
                                              const bf16_t* __restrict__ vt,
                                              bf16_t* __restrict__ ao) {
  constexpr int S = 2048, D = 64, H = 16, KV = 4, WIN = 512;
  const int qblk = blockIdx.x, h = blockIdx.y, b = blockIdx.z;
  const int lane = threadIdx.x & 63, wid = threadIdx.x >> 6;
  const int lr = lane & 15, lg = lane >> 4;
  const int qbase = qblk * 64 + wid * 16;
  const int kv = h >> 2;

  __shared__ __align__(16) bf16_t pl[4][16 * 40];   // per-wave P tile, 80B rows
  bf16_t* pw = pl[wid];

  const bf16_t* qp = qn + ((size_t)(b * H + h) * S + qbase) * D + lr * D + lg * 8;
  bf16x8 qa0 = *reinterpret_cast<const bf16x8*>(qp);
  bf16x8 qa1 = *reinterpret_cast<const bf16x8*>(qp + 32);

  const bf16_t* kb = kn + (size_t)(b * KV + kv) * S * D;
  const bf16_t* vb = vt + (size_t)(b * KV + kv) * D * S;

  const float L2E = 1.4426950408889634f;
  const float c1 = L2E / 8.0f;                      // log2e / sqrt(D)
  const float c2 = exp2f(-0.5f * (float)h) * L2E;   // slope_h * log2e

  f32x4 acc[4] = {};
  float m2[4] = { -__builtin_inff(), -__builtin_inff(), -__builtin_inff(), -__builtin_inff() };
  float ls[4] = {};

  const int kt0 = (qbase > WIN ? qbase - WIN : 0) >> 5;
  const int kt1 = (qbase + 15) >> 5;
  for (int kt = kt0; kt <= kt1; ++kt) {
    const int k0 = kt << 5;
    // ---- S = Q K^T (16q x 32k) ----
    f32x4 sf0 = {}, sf1 = {};
    {
      const bf16_t* kp0 = kb + (size_t)(k0 + lr) * D + lg * 8;
      bf16x8 kf = *reinterpret_cast<const bf16x8*>(kp0);
      sf0 = mfma16(qa0, kf, sf0);
      kf = *reinterpret_cast<const bf16x8*>(kp0 + 32);
      sf0 = mfma16(qa1, kf, sf0);
      const bf16_t* kp1 = kb + (size_t)(k0 + 16 + lr) * D + lg * 8;
      kf = *reinterpret_cast<const bf16x8*>(kp1);
      sf1 = mfma16(qa0, kf, sf1);
      kf = *reinterpret_cast<const bf16x8*>(kp1 + 32);
      sf1 = mfma16(qa1, kf, sf1);
    }
    // ---- bias + mask + row max ----
    float p0[4], p1[4], mx[4];
#pragma unroll
    for (int r = 0; r < 4; ++r) {
      const int i = qbase + lg * 4 + r;
      const int rel0 = (k0 + lr) - i;
      const int rel1 = rel0 + 16;
      float s0 = sf0[r] * c1 + c2 * (float)rel0;
      float s1 = sf1[r] * c1 + c2 * (float)rel1;
      s0 = (rel0 <= 0 && rel0 >= -WIN) ? s0 : -__builtin_inff();
      s1 = (rel1 <= 0 && rel1 >= -WIN) ? s1 : -__builtin_inff();
      p0[r] = s0; p1[r] = s1;
      mx[r] = fmaxf(s0, s1);
    }
#pragma unroll
    for (int d = 1; d < 16; d <<= 1)
#pragma unroll
      for (int r = 0; r < 4; ++r)
        mx[r] = fmaxf(mx[r], __shfl_xor(mx[r], d, 64));
    // ---- online softmax update ----
    float scale[4], rs[4];
#pragma unroll
    for (int r = 0; r < 4; ++r) {
      float mn = fmaxf(m2[r], mx[r]);
      float msafe = (mn == -__builtin_inff()) ? 0.0f : mn;
      scale[r] = exp2f(m2[r] - msafe);     // m2=-inf -> 0
      m2[r] = mn;
      float e0 = exp2f(p0[r] - msafe);
      float e1 = exp2f(p1[r] - msafe);
      p0[r] = e0; p1[r] = e1;
      rs[r] = e0 + e1;
    }
#pragma unroll
    for (int d = 1; d < 16; d <<= 1)
#pragma unroll
      for (int r = 0; r < 4; ++r)
        rs[r] += __shfl_xor(rs[r], d, 64);
#pragma unroll
    for (int r = 0; r < 4; ++r) {
      ls[r] = ls[r] * scale[r] + rs[r];
      const int qrow = lg * 4 + r;
      pw[qrow * 40 + lr] = (bf16_t)p0[r];
      pw[qrow * 40 + 16 + lr] = (bf16_t)p1[r];
    }
    asm volatile("s_waitcnt lgkmcnt(0)" ::: "memory");   // cross-lane LDS RAW within wave
    // ---- PV: out += P @ V ----
    bf16x8 pa = *reinterpret_cast<const bf16x8*>(pw + lr * 40 + lg * 8);
#pragma unroll
    for (int nf = 0; nf < 4; ++nf) {
      const bf16_t* vp = vb + (size_t)(nf * 16 + lr) * S + k0 + lg * 8;
      bf16x8 vf = *reinterpret_cast<const bf16x8*>(vp);
      f32x4 a = acc[nf];
      a[0] *= scale[0]; a[1] *= scale[1]; a[2] *= scale[2]; a[3] *= scale[3];
      acc[nf] = mfma16(pa, vf, a);
    }
  }
  // ---- epilogue: normalize + store [b][s][h*64+d] bf16 ----
#pragma unroll
  for (int nf = 0; nf < 4; ++nf)
#pragma unroll
    for (int r = 0; r < 4; ++r) {
      float o = acc[nf][r] / ls[r];
      ao[((size_t)(b * S + qbase + lg * 4 + r)) * 1024 + h * 64 + nf * 16 + lr] = (bf16_t)o;
    }
}

extern "C" void kernel_launch(void* const* d_in, const int* in_sizes, int n_in,
                              void* d_out, int out_size, void* d_ws, size_t ws_size,
                              hipStream_t stream) {
  const float* features = (const float*)d_in[0];   // [2,2048,1024]
  const float* wq = (const float*)d_in[1];         // [1024,1024]
  const float* wk = (const float*)d_in[2];         // [256,1024]
  const float* wv = (const float*)d_in[3];         // [256,1024]
  const float* wo = (const float*)d_in[4];         // [1024,1024]
  const float* qw = (const float*)d_in[5];         // [1024]
  const float* kw = (const float*)d_in[6];         // [256]
  float* out = (float*)d_out;                      // [4096,1024] f32

  // workspace layout (bf16 elems unless noted)
  bf16_t* Xbf  = (bf16_t*)d_ws;                    // 4096*1024
  bf16_t* Wqkv = Xbf + 4096 * 1024;                // 1536*1024 (wq;wk;wv)
  bf16_t* Wo   = Wqkv + 1536 * 1024;               // 1024*1024
  float*  QKVr = (float*)(Wo + 1024 * 1024);       // 4096*1536 f32
  bf16_t* Qn   = (bf16_t*)(QKVr + 4096 * 1536);    // [2,16,2048,64]
  bf16_t* Kn   = Qn + 2 * 16 * 2048 * 64;          // [2,4,2048,64]
  bf16_t* Vt   = Kn + 2 * 4 * 2048 * 64;           // [2,4,64,2048]
  bf16_t* Ao   = Vt + 2 * 4 * 64 * 2048;           // [4096,1024]

  cast_bf16_k<<<4096, 256, 0, stream>>>(features, Xbf, 1048576);
  cast_bf16_k<<<1024, 256, 0, stream>>>(wq, Wqkv, 262144);
  cast_bf16_k<<<256, 256, 0, stream>>>(wk, Wqkv + 1024 * 1024, 65536);
  cast_bf16_k<<<256, 256, 0, stream>>>(wv, Wqkv + 1280 * 1024, 65536);
  cast_bf16_k<<<1024, 256, 0, stream>>>(wo, Wo, 262144);

  gemm_bt<<<dim3(12, 32), 256, 0, stream>>>(Xbf, Wqkv, QKVr, 4096, 1536, 1024);
  rmsnorm_k<<<4096, 256, 0, stream>>>(QKVr, qw, kw, Qn, Kn);
  transpose_v_k<<<dim3(32, 8), 256, 0, stream>>>(QKVr, Vt);
  attn_k<<<dim3(32, 16, 2), 256, 0, stream>>>(Qn, Kn, Vt, Ao);
  gemm_bt<<<dim3(8, 32), 256, 0, stream>>>(Ao, Wo, out, 4096, 1024, 1024);
}

// Round 2
// 112.543 us; speedup vs baseline: 1.3553x; 1.3553x over previous
//
#include <hip/hip_runtime.h>
#include <hip/hip_bf16.h>

typedef __bf16 bf16_t;
typedef bf16_t bf16x8 __attribute__((ext_vector_type(8)));
typedef bf16_t bf16x4 __attribute__((ext_vector_type(4)));
typedef float  f32x4  __attribute__((ext_vector_type(4)));
typedef float  f32x16 __attribute__((ext_vector_type(16)));

__device__ __forceinline__ f32x4 mfma16(bf16x8 a, bf16x8 b, f32x4 c) {
  return __builtin_amdgcn_mfma_f32_16x16x32_bf16(a, b, c, 0, 0, 0);
}
__device__ __forceinline__ f32x16 mfma32(bf16x8 a, bf16x8 b, f32x16 c) {
  return __builtin_amdgcn_mfma_f32_32x32x16_bf16(a, b, c, 0, 0, 0);
}

// ---------------- cast f32 -> bf16 (vectorized x4) ----------------
__global__ __launch_bounds__(256) void cast_bf16_k(const float* __restrict__ in,
                                                   bf16_t* __restrict__ out, int n4) {
  int i = blockIdx.x * 256 + threadIdx.x;
  if (i >= n4) return;
  float4 v = reinterpret_cast<const float4*>(in)[i];
  bf16x4 o = { (bf16_t)v.x, (bf16_t)v.y, (bf16_t)v.z, (bf16_t)v.w };
  reinterpret_cast<bf16x4*>(out)[i] = o;
}

// ---------------- GEMM: C[M,N] = A[M,K] * B[N,K]^T, bf16 in, f32 out ------------
__global__ __launch_bounds__(256) void gemm_bt(const bf16_t* __restrict__ A,
                                               const bf16_t* __restrict__ B,
                                               float* __restrict__ C,
                                               int M, int N, int K) {
  __shared__ __align__(16) unsigned short sA[128 * 64];
  __shared__ __align__(16) unsigned short sB[128 * 64];
  const int tid = threadIdx.x;
  const int lane = tid & 63;
  const int wid = tid >> 6;
  const int wm = wid >> 1, wn = wid & 1;
  const int lr = lane & 15, lg = lane >> 4;
  const int m0 = blockIdx.y * 128, n0 = blockIdx.x * 128;

  f32x4 acc[4][4] = {};

  for (int k0 = 0; k0 < K; k0 += 64) {
#pragma unroll
    for (int r = 0; r < 4; ++r) {
      int e = r * 2048 + tid * 8;
      int row = e >> 6;
      int c = ((e >> 3) & 7) ^ (row & 7);
      const bf16_t* ga = A + (size_t)(m0 + row) * K + k0 + c * 8;
      __builtin_amdgcn_global_load_lds(
          (const __attribute__((address_space(1))) void*)ga,
          (__attribute__((address_space(3))) void*)(sA + r * 2048 + wid * 512), 16, 0, 0);
      const bf16_t* gb = B + (size_t)(n0 + row) * K + k0 + c * 8;
      __builtin_amdgcn_global_load_lds(
          (const __attribute__((address_space(1))) void*)gb,
          (__attribute__((address_space(3))) void*)(sB + r * 2048 + wid * 512), 16, 0, 0);
    }
    __syncthreads();
#pragma unroll
    for (int ks = 0; ks < 2; ++ks) {
      bf16x8 afr[4], bfr[4];
#pragma unroll
      for (int m = 0; m < 4; ++m) {
        int row = wm * 64 + m * 16 + lr;
        int sc = (ks * 4 + lg) ^ (row & 7);
        afr[m] = *reinterpret_cast<const bf16x8*>(sA + row * 64 + sc * 8);
      }
#pragma unroll
      for (int n = 0; n < 4; ++n) {
        int row = wn * 64 + n * 16 + lr;
        int sc = (ks * 4 + lg) ^ (row & 7);
        bfr[n] = *reinterpret_cast<const bf16x8*>(sB + row * 64 + sc * 8);
      }
#pragma unroll
      for (int m = 0; m < 4; ++m)
#pragma unroll
        for (int n = 0; n < 4; ++n)
          acc[m][n] = mfma16(afr[m], bfr[n], acc[m][n]);
    }
    __syncthreads();
  }
#pragma unroll
  for (int m = 0; m < 4; ++m)
#pragma unroll
    for (int n = 0; n < 4; ++n) {
      int row = m0 + wm * 64 + m * 16 + lg * 4;
      int col = n0 + wn * 64 + n * 16 + lr;
#pragma unroll
      for (int r2 = 0; r2 < 4; ++r2)
        C[(size_t)(row + r2) * N + col] = acc[m][n][r2];
    }
}

// ---------------- RMSNorm of q (1024) and k (256) rows, emit bf16 ----------------
__global__ __launch_bounds__(256) void rmsnorm_k(const float* __restrict__ qkv,
                                                 const float* __restrict__ qw,
                                                 const float* __restrict__ kw,
                                                 bf16_t* __restrict__ qn,
                                                 bf16_t* __restrict__ kn) {
  const int row = blockIdx.x;
  const int b = row >> 11, s = row & 2047;
  const int tid = threadIdx.x;
  const float* rp = qkv + (size_t)row * 1536;
  float4 q4 = *reinterpret_cast<const float4*>(rp + tid * 4);
  float kv1 = rp[1024 + tid];
  float sq = q4.x * q4.x + q4.y * q4.y + q4.z * q4.z + q4.w * q4.w;
  float sk = kv1 * kv1;
#pragma unroll
  for (int d = 1; d < 64; d <<= 1) {
    sq += __shfl_xor(sq, d, 64);
    sk += __shfl_xor(sk, d, 64);
  }
  __shared__ float red[2][4];
  if ((tid & 63) == 0) { red[0][tid >> 6] = sq; red[1][tid >> 6] = sk; }
  __syncthreads();
  sq = red[0][0] + red[0][1] + red[0][2] + red[0][3];
  sk = red[1][0] + red[1][1] + red[1][2] + red[1][3];
  const float rq = rsqrtf(sq * (1.0f / 1024.0f) + 1e-6f);
  const float rk = rsqrtf(sk * (1.0f / 256.0f) + 1e-6f);
  float4 w4 = *reinterpret_cast<const float4*>(qw + tid * 4);
  const int c = tid * 4, hh = c >> 6, d0 = c & 63;
  bf16x4 o = { (bf16_t)(q4.x * rq * w4.x), (bf16_t)(q4.y * rq * w4.y),
               (bf16_t)(q4.z * rq * w4.z), (bf16_t)(q4.w * rq * w4.w) };
  *reinterpret_cast<bf16x4*>(qn + ((size_t)((b * 16 + hh) * 2048 + s)) * 64 + d0) = o;
  const int kvh = tid >> 6, dk = tid & 63;
  kn[((size_t)((b * 4 + kvh) * 2048 + s)) * 64 + dk] = (bf16_t)(kv1 * rk * kw[tid]);
}

// ---------------- V transpose: qkv[.,1280+kv*64+d] -> vt[b][kv][d][s] bf16 -------
__global__ __launch_bounds__(256) void transpose_v_k(const float* __restrict__ qkv,
                                                     bf16_t* __restrict__ vt) {
  __shared__ float t[64][65];
  const int s0 = blockIdx.x * 64;
  const int b = blockIdx.y >> 2, kv = blockIdx.y & 3;
  const int tid = threadIdx.x;
  const int r = tid >> 2, cg = (tid & 3) * 16;
  const float* src = qkv + (size_t)(b * 2048 + s0 + r) * 1536 + 1280 + kv * 64 + cg;
#pragma unroll
  for (int j = 0; j < 4; ++j) {
    float4 v = *reinterpret_cast<const float4*>(src + j * 4);
    t[r][cg + j * 4 + 0] = v.x; t[r][cg + j * 4 + 1] = v.y;
    t[r][cg + j * 4 + 2] = v.z; t[r][cg + j * 4 + 3] = v.w;
  }
  __syncthreads();
  const int dl = tid >> 4;
  const int sl = (tid & 15) * 4;
#pragma unroll
  for (int p = 0; p < 4; ++p) {
    const int d = dl + p * 16;
    bf16x4 o = { (bf16_t)t[sl + 0][d], (bf16_t)t[sl + 1][d],
                 (bf16_t)t[sl + 2][d], (bf16_t)t[sl + 3][d] };
    *reinterpret_cast<bf16x4*>(vt + ((size_t)((b * 4 + kv) * 64 + d)) * 2048 + s0 + sl) = o;
  }
}

// ---------------- Flash attention, swapped-QK 32x32 in-register softmax ----------
// 4 waves/block, 32 q-rows per wave, 32-key tiles processed DESCENDING (diagonal
// first) with defer-max (THR=8 in exp2 domain). A=K,B=Q puts P lane-local:
// lane (c=lane&31, hi=lane>>5) holds P[k=(r&3)+8*(r>>2)+4*hi][q=c].
__global__ __launch_bounds__(256) void attn_k(const bf16_t* __restrict__ qn,
                                              const bf16_t* __restrict__ kn,
                                              const bf16_t* __restrict__ vt,
                                              bf16_t* __restrict__ ao) {
  constexpr int S = 2048, D = 64, H = 16, KV = 4, WIN = 512;
  const int wid = threadIdx.x >> 6;
  const int qblk = blockIdx.x * 4 + wid;          // 32-row q block
  const int h = blockIdx.y, b = blockIdx.z;
  const int kv = h >> 2;
  const int lane = threadIdx.x & 63;
  const int c = lane & 31;                        // q for P, d for O
  const int hi = lane >> 5;
  const int qbase = qblk * 32;
  const int q = qbase + c;

  // Q B-fragment: 4 d-chunks
  const bf16_t* qp = qn + ((size_t)(b * H + h) * S + q) * D + hi * 8;
  bf16x8 qf[4];
#pragma unroll
  for (int cd = 0; cd < 4; ++cd) qf[cd] = *reinterpret_cast<const bf16x8*>(qp + cd * 16);

  const bf16_t* kb = kn + (size_t)(b * KV + kv) * S * D;
  const bf16_t* vb = vt + (size_t)(b * KV + kv) * D * S;

  const float L2E = 1.4426950408889634f;
  const float c1 = L2E / 8.0f;                    // log2e / sqrt(D)
  const float c2 = exp2f(-0.5f * (float)h) * L2E; // slope_h * log2e

  f32x16 acc0 = {}, acc1 = {};                    // O: rows=q(regs), col=d=c / c+32
  float m_run = -3.0e38f, l_run = 0.0f;

  const int ktTop = qbase >> 5;
  const int kt0 = (qbase >= WIN) ? ((qbase - WIN) >> 5) : 0;

  for (int kt = ktTop; kt >= kt0; --kt) {
    const int k0 = kt << 5;
    // ---- QK^T (swapped): A=K rows, B=Q rows ----
    const bf16_t* kp = kb + (size_t)(k0 + c) * D + hi * 8;
    f32x16 sfa = {};
#pragma unroll
    for (int cd = 0; cd < 4; ++cd) {
      bf16x8 kf = *reinterpret_cast<const bf16x8*>(kp + cd * 16);
      sfa = mfma32(kf, qf[cd], sfa);
    }
    // ---- bias + (edge) mask + row max ----
    const bool mtop = (kt == ktTop);
    const bool mbot = (k0 + WIN < qbase + 32);
    float t[16];
    float pmax = -3.0e38f;
    if (mtop | mbot) {
#pragma unroll
      for (int r = 0; r < 16; ++r) {
        const int kk = k0 + (r & 3) + 8 * (r >> 2) + 4 * hi;
        const int rel = kk - q;
        float tv = sfa[r] * c1 + c2 * (float)rel;
        if (rel > 0 || rel < -WIN) tv = -3.0e38f;
        t[r] = tv;
        pmax = fmaxf(pmax, tv);
      }
    } else {
      const float bb = c2 * (float)(k0 + 4 * hi - q);
#pragma unroll
      for (int r = 0; r < 16; ++r) {
        const float koff = (float)((r & 3) + 8 * (r >> 2));
        float tv = fmaf(sfa[r], c1, fmaf(koff, c2, bb));
        t[r] = tv;
        pmax = fmaxf(pmax, tv);
      }
    }
    pmax = fmaxf(pmax, __shfl_xor(pmax, 32, 64));
    // ---- defer-max: rescale only when the running max actually grows ----
    if (!__all(pmax <= m_run + 8.0f)) {
      const float mnew = fmaxf(m_run, pmax);
      const float sc = exp2f(m_run - mnew);
      m_run = mnew;
      l_run *= sc;
#pragma unroll
      for (int r = 0; r < 16; ++r) {
        const int qi = (r & 3) + 8 * (r >> 2) + 4 * hi;
        const float scr = __shfl(sc, qi, 64);
        acc0[r] *= scr;
        acc1[r] *= scr;
      }
    }
    // ---- P = exp2(t - m), bf16 pack (compiler fuses to v_cvt_pk_bf16_f32) ----
    float rs = 0.0f;
    unsigned w[8];
#pragma unroll
    for (int i = 0; i < 8; ++i) {
      float e0 = exp2f(t[2 * i] - m_run);
      float e1 = exp2f(t[2 * i + 1] - m_run);
      rs += e0 + e1;
      union { bf16_t hh[2]; unsigned u; } pk;
      pk.hh[0] = (bf16_t)e0; pk.hh[1] = (bf16_t)e1;
      w[i] = pk.u;
    }
    rs += __shfl_xor(rs, 32, 64);
    l_run += rs;
    // ---- assemble P A-fragments (k in 16-chunks) via cross-hi word swaps ----
    unsigned s0 = __shfl_xor(w[0], 32, 64), s1 = __shfl_xor(w[1], 32, 64);
    unsigned s2 = __shfl_xor(w[2], 32, 64), s3 = __shfl_xor(w[3], 32, 64);
    unsigned s4 = __shfl_xor(w[4], 32, 64), s5 = __shfl_xor(w[5], 32, 64);
    unsigned s6 = __shfl_xor(w[6], 32, 64), s7 = __shfl_xor(w[7], 32, 64);
    union { unsigned u[4]; bf16x8 v; } pa0, pa1;
    if (hi == 0) {
      pa0.u[0] = w[0]; pa0.u[1] = w[1]; pa0.u[2] = s0; pa0.u[3] = s1;
      pa1.u[0] = w[4]; pa1.u[1] = w[5]; pa1.u[2] = s4; pa1.u[3] = s5;
    } else {
      pa0.u[0] = s2; pa0.u[1] = s3; pa0.u[2] = w[2]; pa0.u[3] = w[3];
      pa1.u[0] = s6; pa1.u[1] = s7; pa1.u[2] = w[6]; pa1.u[3] = w[7];
    }
    // ---- PV: A=P rows(q), B=V^T rows(d); two k-chunks, two d-halves ----
    const bf16_t* vp = vb + (size_t)c * S + k0 + hi * 8;
    bf16x8 v00 = *reinterpret_cast<const bf16x8*>(vp);
    bf16x8 v01 = *reinterpret_cast<const bf16x8*>(vp + 16);
    bf16x8 v10 = *reinterpret_cast<const bf16x8*>(vp + 32 * S);
    bf16x8 v11 = *reinterpret_cast<const bf16x8*>(vp + 32 * S + 16);
    acc0 = mfma32(pa0.v, v00, acc0);
    acc0 = mfma32(pa1.v, v01, acc0);
    acc1 = mfma32(pa0.v, v10, acc1);
    acc1 = mfma32(pa1.v, v11, acc1);
  }
  // ---- epilogue: normalize (l broadcast per q-reg) + store bf16 ----
#pragma unroll
  for (int r = 0; r < 16; ++r) {
    const int qi = (r & 3) + 8 * (r >> 2) + 4 * hi;
    const float lr = __shfl(l_run, qi, 64);
    const float inv = 1.0f / lr;
    bf16_t* op = ao + ((size_t)(b * S + qbase + qi)) * 1024 + h * 64 + c;
    op[0]  = (bf16_t)(acc0[r] * inv);
    op[32] = (bf16_t)(acc1[r] * inv);
  }
}

extern "C" void kernel_launch(void* const* d_in, const int* in_sizes, int n_in,
                              void* d_out, int out_size, void* d_ws, size_t ws_size,
                              hipStream_t stream) {
  const float* features = (const float*)d_in[0];
  const float* wq = (const float*)d_in[1];
  const float* wk = (const float*)d_in[2];
  const float* wv = (const float*)d_in[3];
  const float* wo = (const float*)d_in[4];
  const float* qw = (const float*)d_in[5];
  const float* kw = (const float*)d_in[6];
  float* out = (float*)d_out;

  bf16_t* Xbf  = (bf16_t*)d_ws;
  bf16_t* Wqkv = Xbf + 4096 * 1024;
  bf16_t* Wo   = Wqkv + 1536 * 1024;
  float*  QKVr = (float*)(Wo + 1024 * 1024);
  bf16_t* Qn   = (bf16_t*)(QKVr + 4096 * 1536);
  bf16_t* Kn   = Qn + 2 * 16 * 2048 * 64;
  bf16_t* Vt   = Kn + 2 * 4 * 2048 * 64;
  bf16_t* Ao   = Vt + 2 * 4 * 64 * 2048;

  cast_bf16_k<<<4096, 256, 0, stream>>>(features, Xbf, 1048576);
  cast_bf16_k<<<1024, 256, 0, stream>>>(wq, Wqkv, 262144);
  cast_bf16_k<<<256, 256, 0, stream>>>(wk, Wqkv + 1024 * 1024, 65536);
  cast_bf16_k<<<256, 256, 0, stream>>>(wv, Wqkv + 1280 * 1024, 65536);
  cast_bf16_k<<<1024, 256, 0, stream>>>(wo, Wo, 262144);

  gemm_bt<<<dim3(12, 32), 256, 0, stream>>>(Xbf, Wqkv, QKVr, 4096, 1536, 1024);
  rmsnorm_k<<<4096, 256, 0, stream>>>(QKVr, qw, kw, Qn, Kn);
  transpose_v_k<<<dim3(32, 8), 256, 0, stream>>>(QKVr, Vt);
  attn_k<<<dim3(16, 16, 2), 256, 0, stream>>>(Qn, Kn, Vt, Ao);
  gemm_bt<<<dim3(8, 32), 256, 0, stream>>>(Ao, Wo, out, 4096, 1024, 1024);
}

// Round 4
// 104.016 us; speedup vs baseline: 1.4664x; 1.0820x over previous
//
#include <hip/hip_runtime.h>
#include <hip/hip_bf16.h>

typedef __bf16 bf16_t;
typedef bf16_t bf16x8 __attribute__((ext_vector_type(8)));
typedef bf16_t bf16x4 __attribute__((ext_vector_type(4)));
typedef float  f32x4  __attribute__((ext_vector_type(4)));
typedef float  f32x16 __attribute__((ext_vector_type(16)));

__device__ __forceinline__ f32x4 mfma16(bf16x8 a, bf16x8 b, f32x4 c) {
  return __builtin_amdgcn_mfma_f32_16x16x32_bf16(a, b, c, 0, 0, 0);
}
__device__ __forceinline__ f32x16 mfma32(bf16x8 a, bf16x8 b, f32x16 c) {
  return __builtin_amdgcn_mfma_f32_32x32x16_bf16(a, b, c, 0, 0, 0);
}

// ---------------- fused cast f32 -> bf16 for all 5 tensors ----------------
// regions in float4 units:
// features [0,1048576) | wq [..,1310720) | wk [..,1376256) | wv [..,1441792) | wo [..,1703936)
__global__ __launch_bounds__(256) void cast_all_k(const float* __restrict__ f,
                                                  const float* __restrict__ wq,
                                                  const float* __restrict__ wk,
                                                  const float* __restrict__ wv,
                                                  const float* __restrict__ wo,
                                                  bf16_t* __restrict__ Xbf,
                                                  bf16_t* __restrict__ Wqkv,
                                                  bf16_t* __restrict__ Wo) {
  int i = blockIdx.x * 256 + threadIdx.x;
  const float* src; bf16_t* dst; int off;
  if (i < 1048576)      { src = f;  dst = Xbf;                 off = 0; }
  else if (i < 1310720) { src = wq; dst = Wqkv;                off = 1048576; }
  else if (i < 1376256) { src = wk; dst = Wqkv + 1024 * 1024;  off = 1310720; }
  else if (i < 1441792) { src = wv; dst = Wqkv + 1280 * 1024;  off = 1376256; }
  else if (i < 1703936) { src = wo; dst = Wo;                  off = 1441792; }
  else return;
  int j = i - off;
  float4 v = reinterpret_cast<const float4*>(src)[j];
  bf16x4 o = { (bf16_t)v.x, (bf16_t)v.y, (bf16_t)v.z, (bf16_t)v.w };
  reinterpret_cast<bf16x4*>(dst)[j] = o;
}

// ---------------- GEMM: C[M,N] = A[M,K] * B[N,K]^T, bf16 in, f32 out ------------
// 128x128 tile, BK=64, 4 waves, double-buffered LDS: STAGE(t+1) issued BEFORE
// compute(t); single barrier per tile drains late (issue-early/drain-late).
__global__ __launch_bounds__(256) void gemm_bt(const bf16_t* __restrict__ A,
                                               const bf16_t* __restrict__ B,
                                               float* __restrict__ C,
                                               int M, int N, int K) {
  __shared__ __align__(16) unsigned short sA[2][128 * 64];
  __shared__ __align__(16) unsigned short sB[2][128 * 64];
  const int tid = threadIdx.x;
  const int lane = tid & 63;
  const int wid = tid >> 6;
  const int wm = wid >> 1, wn = wid & 1;
  const int lr = lane & 15, lg = lane >> 4;
  const int m0 = blockIdx.y * 128, n0 = blockIdx.x * 128;

  f32x4 acc[4][4] = {};

  auto STAGE = [&](int buf, int k0) {
#pragma unroll
    for (int r = 0; r < 4; ++r) {
      int e = r * 2048 + tid * 8;
      int row = e >> 6;
      int c = ((e >> 3) & 7) ^ (row & 7);
      const bf16_t* ga = A + (size_t)(m0 + row) * K + k0 + c * 8;
      __builtin_amdgcn_global_load_lds(
          (const __attribute__((address_space(1))) void*)ga,
          (__attribute__((address_space(3))) void*)(&sA[buf][r * 2048 + wid * 512]), 16, 0, 0);
      const bf16_t* gb = B + (size_t)(n0 + row) * K + k0 + c * 8;
      __builtin_amdgcn_global_load_lds(
          (const __attribute__((address_space(1))) void*)gb,
          (__attribute__((address_space(3))) void*)(&sB[buf][r * 2048 + wid * 512]), 16, 0, 0);
    }
  };

  const int nt = K >> 6;
  STAGE(0, 0);
  __syncthreads();                       // prologue drain (exposed once)
  int cur = 0;
  for (int t = 0; t < nt; ++t) {
    if (t + 1 < nt) STAGE(cur ^ 1, (t + 1) << 6);
#pragma unroll
    for (int ks = 0; ks < 2; ++ks) {
      bf16x8 afr[4], bfr[4];
#pragma unroll
      for (int m = 0; m < 4; ++m) {
        int row = wm * 64 + m * 16 + lr;
        int sc = (ks * 4 + lg) ^ (row & 7);
        afr[m] = *reinterpret_cast<const bf16x8*>(&sA[cur][row * 64 + sc * 8]);
      }
#pragma unroll
      for (int n = 0; n < 4; ++n) {
        int row = wn * 64 + n * 16 + lr;
        int sc = (ks * 4 + lg) ^ (row & 7);
        bfr[n] = *reinterpret_cast<const bf16x8*>(&sB[cur][row * 64 + sc * 8]);
      }
#pragma unroll
      for (int m = 0; m < 4; ++m)
#pragma unroll
        for (int n = 0; n < 4; ++n)
          acc[m][n] = mfma16(afr[m], bfr[n], acc[m][n]);
    }
    __syncthreads();                     // drains STAGE(t+1) + this tile's reads
    cur ^= 1;
  }
#pragma unroll
  for (int m = 0; m < 4; ++m)
#pragma unroll
    for (int n = 0; n < 4; ++n) {
      int row = m0 + wm * 64 + m * 16 + lg * 4;
      int col = n0 + wn * 64 + n * 16 + lr;
#pragma unroll
      for (int r2 = 0; r2 < 4; ++r2)
        C[(size_t)(row + r2) * N + col] = acc[m][n][r2];
    }
}

// ---------------- RMSNorm of q (1024) and k (256) rows, emit bf16 ----------------
__global__ __launch_bounds__(256) void rmsnorm_k(const float* __restrict__ qkv,
                                                 const float* __restrict__ qw,
                                                 const float* __restrict__ kw,
                                                 bf16_t* __restrict__ qn,
                                                 bf16_t* __restrict__ kn) {
  const int row = blockIdx.x;
  const int b = row >> 11, s = row & 2047;
  const int tid = threadIdx.x;
  const float* rp = qkv + (size_t)row * 1536;
  float4 q4 = *reinterpret_cast<const float4*>(rp + tid * 4);
  float kv1 = rp[1024 + tid];
  float sq = q4.x * q4.x + q4.y * q4.y + q4.z * q4.z + q4.w * q4.w;
  float sk = kv1 * kv1;
#pragma unroll
  for (int d = 1; d < 64; d <<= 1) {
    sq += __shfl_xor(sq, d, 64);
    sk += __shfl_xor(sk, d, 64);
  }
  __shared__ float red[2][4];
  if ((tid & 63) == 0) { red[0][tid >> 6] = sq; red[1][tid >> 6] = sk; }
  __syncthreads();
  sq = red[0][0] + red[0][1] + red[0][2] + red[0][3];
  sk = red[1][0] + red[1][1] + red[1][2] + red[1][3];
  const float rq = rsqrtf(sq * (1.0f / 1024.0f) + 1e-6f);
  const float rk = rsqrtf(sk * (1.0f / 256.0f) + 1e-6f);
  float4 w4 = *reinterpret_cast<const float4*>(qw + tid * 4);
  const int c = tid * 4, hh = c >> 6, d0 = c & 63;
  bf16x4 o = { (bf16_t)(q4.x * rq * w4.x), (bf16_t)(q4.y * rq * w4.y),
               (bf16_t)(q4.z * rq * w4.z), (bf16_t)(q4.w * rq * w4.w) };
  *reinterpret_cast<bf16x4*>(qn + ((size_t)((b * 16 + hh) * 2048 + s)) * 64 + d0) = o;
  const int kvh = tid >> 6, dk = tid & 63;
  kn[((size_t)((b * 4 + kvh) * 2048 + s)) * 64 + dk] = (bf16_t)(kv1 * rk * kw[tid]);
}

// ---------------- V transpose: qkv[.,1280+kv*64+d] -> vt[b][kv][d][s] bf16 -------
__global__ __launch_bounds__(256) void transpose_v_k(const float* __restrict__ qkv,
                                                     bf16_t* __restrict__ vt) {
  __shared__ float t[64][65];
  const int s0 = blockIdx.x * 64;
  const int b = blockIdx.y >> 2, kv = blockIdx.y & 3;
  const int tid = threadIdx.x;
  const int r = tid >> 2, cg = (tid & 3) * 16;
  const float* src = qkv + (size_t)(b * 2048 + s0 + r) * 1536 + 1280 + kv * 64 + cg;
#pragma unroll
  for (int j = 0; j < 4; ++j) {
    float4 v = *reinterpret_cast<const float4*>(src + j * 4);
    t[r][cg + j * 4 + 0] = v.x; t[r][cg + j * 4 + 1] = v.y;
    t[r][cg + j * 4 + 2] = v.z; t[r][cg + j * 4 + 3] = v.w;
  }
  __syncthreads();
  const int dl = tid >> 4;
  const int sl = (tid & 15) * 4;
#pragma unroll
  for (int p = 0; p < 4; ++p) {
    const int d = dl + p * 16;
    bf16x4 o = { (bf16_t)t[sl + 0][d], (bf16_t)t[sl + 1][d],
                 (bf16_t)t[sl + 2][d], (bf16_t)t[sl + 3][d] };
    *reinterpret_cast<bf16x4*>(vt + ((size_t)((b * 4 + kv) * 64 + d)) * 2048 + s0 + sl) = o;
  }
}

// ---------------- Flash attention, swapped-QK 32x32, 2-wave k-split --------------
// Each 32-q block is shared by 2 waves (kh=0,1) taking interleaved 32-key tiles
// descending from the diagonal; partial (m,l,acc) merged in LDS at the end.
__global__ __launch_bounds__(256, 4) void attn_k(const bf16_t* __restrict__ qn,
                                                 const bf16_t* __restrict__ kn,
                                                 const bf16_t* __restrict__ vt,
                                                 bf16_t* __restrict__ ao) {
  constexpr int S = 2048, D = 64, H = 16, KV = 4, WIN = 512;
  const int wid = threadIdx.x >> 6;
  const int pair = wid >> 1;                      // which q-block in this block
  const int kh = wid & 1;                         // k-interleave phase
  const int qblk = blockIdx.x * 2 + pair;
  const int h = blockIdx.y, b = blockIdx.z;
  const int kv = h >> 2;
  const int lane = threadIdx.x & 63;
  const int c = lane & 31;                        // q for P, d for O
  const int hi = lane >> 5;
  const int qbase = qblk * 32;
  const int q = qbase + c;

  __shared__ float mls[2][2][2][32];              // [pair][kh][m|l][q]
  __shared__ float accbuf[2][64][33];             // [pair][lane][r], +1 pad

  const bf16_t* qp = qn + ((size_t)(b * H + h) * S + q) * D + hi * 8;
  bf16x8 qf[4];
#pragma unroll
  for (int cd = 0; cd < 4; ++cd) qf[cd] = *reinterpret_cast<const bf16x8*>(qp + cd * 16);

  const bf16_t* kb = kn + (size_t)(b * KV + kv) * S * D;
  const bf16_t* vb = vt + (size_t)(b * KV + kv) * D * S;

  const float L2E = 1.4426950408889634f;
  const float c1 = L2E / 8.0f;                    // log2e / sqrt(D)
  const float c2 = exp2f(-0.5f * (float)h) * L2E; // slope_h * log2e

  f32x16 acc0 = {}, acc1 = {};
  float m_run = -3.0e38f, l_run = 0.0f;

  const int ktTop = qbase >> 5;
  const int kt0 = (qbase >= WIN) ? ((qbase - WIN) >> 5) : 0;

  for (int kt = ktTop - kh; kt >= kt0; kt -= 2) {
    const int k0 = kt << 5;
    // ---- QK^T (swapped): A=K rows, B=Q rows ----
    const bf16_t* kp = kb + (size_t)(k0 + c) * D + hi * 8;
    f32x16 sfa = {};
#pragma unroll
    for (int cd = 0; cd < 4; ++cd) {
      bf16x8 kf = *reinterpret_cast<const bf16x8*>(kp + cd * 16);
      sfa = mfma32(kf, qf[cd], sfa);
    }
    // ---- bias + (edge) mask + row max ----
    const bool mtop = (kt == ktTop);
    const bool mbot = (k0 + WIN < qbase + 32);
    float t[16];
    float pmax = -3.0e38f;
    if (mtop | mbot) {
#pragma unroll
      for (int r = 0; r < 16; ++r) {
        const int kk = k0 + (r & 3) + 8 * (r >> 2) + 4 * hi;
        const int rel = kk - q;
        float tv = sfa[r] * c1 + c2 * (float)rel;
        if (rel > 0 || rel < -WIN) tv = -3.0e38f;
        t[r] = tv;
        pmax = fmaxf(pmax, tv);
      }
    } else {
      const float bb = c2 * (float)(k0 + 4 * hi - q);
#pragma unroll
      for (int r = 0; r < 16; ++r) {
        const float koff = (float)((r & 3) + 8 * (r >> 2));
        float tv = fmaf(sfa[r], c1, fmaf(koff, c2, bb));
        t[r] = tv;
        pmax = fmaxf(pmax, tv);
      }
    }
    pmax = fmaxf(pmax, __shfl_xor(pmax, 32, 64));
    // ---- defer-max rescale ----
    if (!__all(pmax <= m_run + 8.0f)) {
      const float mnew = fmaxf(m_run, pmax);
      const float sc = exp2f(m_run - mnew);
      m_run = mnew;
      l_run *= sc;
#pragma unroll
      for (int r = 0; r < 16; ++r) {
        const int qi = (r & 3) + 8 * (r >> 2) + 4 * hi;
        const float scr = __shfl(sc, qi, 64);
        acc0[r] *= scr;
        acc1[r] *= scr;
      }
    }
    // ---- P = exp2(t - m), packed bf16 ----
    float rs = 0.0f;
    unsigned w[8];
#pragma unroll
    for (int i = 0; i < 8; ++i) {
      float e0 = exp2f(t[2 * i] - m_run);
      float e1 = exp2f(t[2 * i + 1] - m_run);
      rs += e0 + e1;
      union { bf16_t hh[2]; unsigned u; } pk;
      pk.hh[0] = (bf16_t)e0; pk.hh[1] = (bf16_t)e1;
      w[i] = pk.u;
    }
    rs += __shfl_xor(rs, 32, 64);
    l_run += rs;
    // ---- assemble P A-fragments via cross-hi word swaps ----
    unsigned s0 = __shfl_xor(w[0], 32, 64), s1 = __shfl_xor(w[1], 32, 64);
    unsigned s2 = __shfl_xor(w[2], 32, 64), s3 = __shfl_xor(w[3], 32, 64);
    unsigned s4 = __shfl_xor(w[4], 32, 64), s5 = __shfl_xor(w[5], 32, 64);
    unsigned s6 = __shfl_xor(w[6], 32, 64), s7 = __shfl_xor(w[7], 32, 64);
    union { unsigned u[4]; bf16x8 v; } pa0, pa1;
    if (hi == 0) {
      pa0.u[0] = w[0]; pa0.u[1] = w[1]; pa0.u[2] = s0; pa0.u[3] = s1;
      pa1.u[0] = w[4]; pa1.u[1] = w[5]; pa1.u[2] = s4; pa1.u[3] = s5;
    } else {
      pa0.u[0] = s2; pa0.u[1] = s3; pa0.u[2] = w[2]; pa0.u[3] = w[3];
      pa1.u[0] = s6; pa1.u[1] = s7; pa1.u[2] = w[6]; pa1.u[3] = w[7];
    }
    // ---- PV ----
    const bf16_t* vp = vb + (size_t)c * S + k0 + hi * 8;
    bf16x8 v00 = *reinterpret_cast<const bf16x8*>(vp);
    bf16x8 v01 = *reinterpret_cast<const bf16x8*>(vp + 16);
    bf16x8 v10 = *reinterpret_cast<const bf16x8*>(vp + 32 * S);
    bf16x8 v11 = *reinterpret_cast<const bf16x8*>(vp + 32 * S + 16);
    acc0 = mfma32(pa0.v, v00, acc0);
    acc0 = mfma32(pa1.v, v01, acc0);
    acc1 = mfma32(pa0.v, v10, acc1);
    acc1 = mfma32(pa1.v, v11, acc1);
  }

  // ---- merge the two k-half partials ----
  mls[pair][kh][0][c] = m_run;
  mls[pair][kh][1][c] = l_run;
  __syncthreads();
  const float mo = mls[pair][kh ^ 1][0][c];
  const float lo = mls[pair][kh ^ 1][1][c];
  const float mt = fmaxf(m_run, mo);
  const float sc_self = exp2f(m_run - mt);
#pragma unroll
  for (int r = 0; r < 16; ++r) {
    const int qi = (r & 3) + 8 * (r >> 2) + 4 * hi;
    const float scr = __shfl(sc_self, qi, 64);
    acc0[r] *= scr;
    acc1[r] *= scr;
  }
  if (kh == 1) {
#pragma unroll
    for (int r = 0; r < 16; ++r) {
      accbuf[pair][lane][r] = acc0[r];
      accbuf[pair][lane][r + 16] = acc1[r];
    }
  }
  __syncthreads();
  if (kh == 0) {
    const float l_tot = l_run * sc_self + lo * exp2f(mo - mt);
#pragma unroll
    for (int r = 0; r < 16; ++r) {
      acc0[r] += accbuf[pair][lane][r];
      acc1[r] += accbuf[pair][lane][r + 16];
    }
#pragma unroll
    for (int r = 0; r < 16; ++r) {
      const int qi = (r & 3) + 8 * (r >> 2) + 4 * hi;
      const float lr = __shfl(l_tot, qi, 64);
      const float inv = 1.0f / lr;
      bf16_t* op = ao + ((size_t)(b * S + qbase + qi)) * 1024 + h * 64 + c;
      op[0]  = (bf16_t)(acc0[r] * inv);
      op[32] = (bf16_t)(acc1[r] * inv);
    }
  }
}

extern "C" void kernel_launch(void* const* d_in, const int* in_sizes, int n_in,
                              void* d_out, int out_size, void* d_ws, size_t ws_size,
                              hipStream_t stream) {
  const float* features = (const float*)d_in[0];
  const float* wq = (const float*)d_in[1];
  const float* wk = (const float*)d_in[2];
  const float* wv = (const float*)d_in[3];
  const float* wo = (const float*)d_in[4];
  const float* qw = (const float*)d_in[5];
  const float* kw = (const float*)d_in[6];
  float* out = (float*)d_out;

  bf16_t* Xbf  = (bf16_t*)d_ws;
  bf16_t* Wqkv = Xbf + 4096 * 1024;
  bf16_t* Wo   = Wqkv + 1536 * 1024;
  float*  QKVr = (float*)(Wo + 1024 * 1024);
  bf16_t* Qn   = (bf16_t*)(QKVr + 4096 * 1536);
  bf16_t* Kn   = Qn + 2 * 16 * 2048 * 64;
  bf16_t* Vt   = Kn + 2 * 4 * 2048 * 64;
  bf16_t* Ao   = Vt + 2 * 4 * 64 * 2048;

  cast_all_k<<<6656, 256, 0, stream>>>(features, wq, wk, wv, wo, Xbf, Wqkv, Wo);
  gemm_bt<<<dim3(12, 32), 256, 0, stream>>>(Xbf, Wqkv, QKVr, 4096, 1536, 1024);
  rmsnorm_k<<<4096, 256, 0, stream>>>(QKVr, qw, kw, Qn, Kn);
  transpose_v_k<<<dim3(32, 8), 256, 0, stream>>>(QKVr, Vt);
  attn_k<<<dim3(32, 16, 2), 256, 0, stream>>>(Qn, Kn, Vt, Ao);
  gemm_bt<<<dim3(8, 32), 256, 0, stream>>>(Ao, Wo, out, 4096, 1024, 1024);
}